// Round 5
// baseline (305.194 us; speedup 1.0000x reference)
//
#include <hip/hip_runtime.h>

typedef unsigned short u16;
typedef __bf16 bf16x8 __attribute__((ext_vector_type(8)));
typedef float f32x4 __attribute__((ext_vector_type(4)));

// fp32 -> bf16 round-to-nearest-even (finite, small values; no NaN path)
__device__ __forceinline__ u16 f2bf(float f) {
  unsigned int u = __float_as_uint(f);
  return (u16)((u + 0x7fffu + ((u >> 16) & 1u)) >> 16);
}

// cumK(i) = sum_{i'<i} (8-i')*512 = 256*i*(17-i); K_i = (8-i)*512
__device__ __forceinline__ int cumK(int i) { return 256 * i * (17 - i); }

// ---------------------------------------------------------------------------
// Kernel 1: xbar build. For each batch row b:
//   Xb[b, cumK(i) + j*512 + f] = bf16( sum_g C_i[g,j] * x[b, g*512 + f] )
// ---------------------------------------------------------------------------
__global__ __launch_bounds__(256) void k_xbar(
    const float* __restrict__ x,
    const int* p0, const int* p1, const int* p2, const int* p3,
    const int* p4, const int* p5, const int* p6,
    u16* __restrict__ Xb) {
  __shared__ float sc[448];
  const int b = blockIdx.x;
  const int t = threadIdx.x;
  const int* ps[7] = {p0, p1, p2, p3, p4, p5, p6};
  for (int cell = t; cell < 448; cell += 256) {
    int i = cell >> 6, rem = cell & 63, g = rem >> 3, j = rem & 7;
    int scale = 8 - i;
    float v = 0.f;
    if (j < scale) {
      const int* p = ps[i];
      int cnt = 0;
      for (int s = 0; s < 12; ++s) cnt += (p[s * scale + j] == g) ? 1 : 0;
      v = (float)cnt * (1.0f / 12.0f);
    }
    sc[cell] = v;
  }
  __syncthreads();
  const int u = t & 63;
  const int wv = t >> 6;
  const float4* xrow = reinterpret_cast<const float4*>(x + (size_t)b * 4096);
  float4 xr0[8], xr1[8];
#pragma unroll
  for (int g = 0; g < 8; ++g) {
    xr0[g] = xrow[g * 128 + u * 2];
    xr1[g] = xrow[g * 128 + u * 2 + 1];
  }
  u16* orow = Xb + (size_t)b * 17920;
  for (int s = wv; s < 35; s += 4) {
    int i = 0, rem = s;                 // wave-uniform decode of (i, j)
    while (rem >= 8 - i) { rem -= 8 - i; ++i; }
    const int j = rem;
    float4 A0 = make_float4(0.f, 0.f, 0.f, 0.f);
    float4 A1 = make_float4(0.f, 0.f, 0.f, 0.f);
#pragma unroll
    for (int g = 0; g < 8; ++g) {
      const float c = sc[i * 64 + g * 8 + j];
      A0.x += c * xr0[g].x; A0.y += c * xr0[g].y;
      A0.z += c * xr0[g].z; A0.w += c * xr0[g].w;
      A1.x += c * xr1[g].x; A1.y += c * xr1[g].y;
      A1.z += c * xr1[g].z; A1.w += c * xr1[g].w;
    }
    uint4 o;
    o.x = (unsigned)f2bf(A0.x) | ((unsigned)f2bf(A0.y) << 16);
    o.y = (unsigned)f2bf(A0.z) | ((unsigned)f2bf(A0.w) << 16);
    o.z = (unsigned)f2bf(A1.x) | ((unsigned)f2bf(A1.y) << 16);
    o.w = (unsigned)f2bf(A1.z) | ((unsigned)f2bf(A1.w) << 16);
    *reinterpret_cast<uint4*>(orow + cumK(i) + j * 512 + u * 8) = o;
  }
}

// ---------------------------------------------------------------------------
// Kernel 2: cast-copy W_i fp32 -> concatenated bf16 Wcat (linear copy).
// ---------------------------------------------------------------------------
__global__ __launch_bounds__(256) void k_wcast(
    const float* W0, const float* W1, const float* W2, const float* W3,
    const float* W4, const float* W5, const float* W6,
    u16* __restrict__ Wcat) {
  int i = 0, rem = blockIdx.x;
  while (rem >= (8 - i) * 512) { rem -= (8 - i) * 512; ++i; }
  const float* Wi = (i == 0) ? W0 : (i == 1) ? W1 : (i == 2) ? W2 :
                    (i == 3) ? W3 : (i == 4) ? W4 : (i == 5) ? W5 : W6;
  const int t = threadIdx.x;
  const float4 w = reinterpret_cast<const float4*>(Wi)[(size_t)rem * 256 + t];
  ushort4 o;
  o.x = f2bf(w.x); o.y = f2bf(w.y); o.z = f2bf(w.z); o.w = f2bf(w.w);
  reinterpret_cast<ushort4*>(Wcat + ((size_t)cumK(i) + rem) * 1024)[t] = o;
}

// ---------------------------------------------------------------------------
// Kernel 3: multi-scale bf16 MFMA GEMM, 2-stage dbuf, BK=32 (32 KB LDS ->
// 5 blocks/CU; all 896 blocks co-resident -> block-level overlap hides the
// barrier drains that limited the BK=64/2-block version to MfmaUtil 35%).
// Per iter: issue next tile's 4 global_load_lds, s_waitcnt vmcnt(4),
// s_barrier, 8x ds_read_b128 + 16 MFMA, s_barrier.
// LDS rows are 64 B; chunk c of row r stored at slot (c + (r>>1)) & 3 ->
// 16-lane b128 read groups hit all 8 bank-16B-groups 2-way (free).
// XCD swizzle: blockIdx%8 = XCD owns a 4m x 2n region per scale.
// Scale order {0,1,4,2,5,3,6} balances per-CU iter sums (272 vs 288).
// ---------------------------------------------------------------------------
__device__ __forceinline__ void gl_lds16(const u16* g, u16* l) {
  __builtin_amdgcn_global_load_lds(
      (const __attribute__((address_space(1))) void*)g,
      (__attribute__((address_space(3))) void*)l, 16, 0, 0);
}

#define WAIT_VM4 0x0F74   // vmcnt=4, expcnt=7(nowait), lgkmcnt=15(nowait)
#define WAIT_VM0 0x0F70   // vmcnt=0, expcnt=7, lgkmcnt=15

__global__ __launch_bounds__(256, 5) void k_gemm_ms(
    const u16* __restrict__ Xb, const u16* __restrict__ Wcat,
    const float* b0, const float* b1, const float* b2, const float* b3,
    const float* b4, const float* b5, const float* b6,
    float* __restrict__ out) {
  __shared__ u16 lds[2 * 8192];       // buf b at b*8192: A [0,4096), B [4096,8192)
  const int r = blockIdx.x >> 7;
  const int i = (r == 0) ? 0 : (r == 1) ? 1 : (r == 2) ? 4 :
                (r == 3) ? 2 : (r == 4) ? 5 : (r == 5) ? 3 : 6;
  const int s = blockIdx.x & 127;
  const int region = s & 7;           // -> XCD (blockIdx % 8)
  const int k = s >> 3;               // 0..15 within region
  const int mq = region >> 1;         // 0..3
  const int nq = region & 1;          // 0..1
  const int m0 = (mq * 4 + (k & 3)) * 128;
  const int n0loc = (nq * 4 + (k >> 2)) * 128;
  const int K = (8 - i) * 512;
  const int niter = K >> 5;           // 128,112,96,80,64,48,32
  const size_t baseB = (size_t)cumK(i) * 1024;

  const int tid = threadIdx.x;
  const int lane = tid & 63;
  const int wave = tid >> 6;
  const int quad = lane >> 4;
  const int l15 = lane & 15;
  const int waveM = (wave >> 1) * 64;
  const int waveN = (wave & 1) * 64;

  // Staging: per matrix, tile = 128 rows x 64 B = 512 chunks of 16 B;
  // 2 chunks/thread (rows t>>2 and t>>2 + 64, same slot t&3).
  // Swizzle slot(r,c) = (c + (r>>1))&3  =>  c = ((t&3) - (t>>3)) & 3.
  const int srow = tid >> 2;          // 0..63
  const int gch = ((tid & 3) - (tid >> 3)) & 3;
  const u16* pA0 = Xb + (size_t)(m0 + srow) * 17920 + cumK(i) + gch * 8;
  const u16* pB0 = Wcat + baseB + (size_t)(n0loc + srow) * K + gch * 8;
  const size_t strideA2 = (size_t)64 * 17920;
  const size_t strideB2 = (size_t)64 * K;
  u16* lA0 = lds + tid * 8;           // chunk t; chunk t+256 at +2048
  u16* lB0 = lds + 4096 + tid * 8;

  // LDS read offsets (u16, within buffer): row*32 + slot(row,quad)*8
  int offA[4], offB[4];
#pragma unroll
  for (int q = 0; q < 4; ++q) {
    int rowA = waveM + q * 16 + l15;
    offA[q] = rowA * 32 + ((quad + (rowA >> 1)) & 3) * 8;
    int rowB = waveN + q * 16 + l15;
    offB[q] = 4096 + rowB * 32 + ((quad + (rowB >> 1)) & 3) * 8;
  }

  f32x4 acc[4][4];
#pragma unroll
  for (int q = 0; q < 4; ++q)
#pragma unroll
    for (int c = 0; c < 4; ++c) {
      f32x4 z = {0.f, 0.f, 0.f, 0.f};
      acc[q][c] = z;
    }

  // Prologue: tile 0 -> buffer 0
  gl_lds16(pA0, lA0);
  gl_lds16(pA0 + strideA2, lA0 + 2048);
  gl_lds16(pB0, lB0);
  gl_lds16(pB0 + strideB2, lB0 + 2048);

  for (int kt = 0; kt < niter - 1; ++kt) {
    // Issue next tile into the other buffer (stays in flight past barrier)
    const size_t ko = (size_t)(kt + 1) * 32;
    const int nb = ((kt + 1) & 1) << 13;
    gl_lds16(pA0 + ko, lA0 + nb);
    gl_lds16(pA0 + strideA2 + ko, lA0 + nb + 2048);
    gl_lds16(pB0 + ko, lB0 + nb);
    gl_lds16(pB0 + strideB2 + ko, lB0 + nb + 2048);
    __builtin_amdgcn_s_waitcnt(WAIT_VM4);   // previous tile's 4 loads done
    __builtin_amdgcn_s_barrier();
    const int boff = (kt & 1) << 13;
    bf16x8 av[4], bv[4];
#pragma unroll
    for (int q = 0; q < 4; ++q) av[q] = *reinterpret_cast<const bf16x8*>(lds + boff + offA[q]);
#pragma unroll
    for (int c = 0; c < 4; ++c) bv[c] = *reinterpret_cast<const bf16x8*>(lds + boff + offB[c]);
#pragma unroll
    for (int q = 0; q < 4; ++q)
#pragma unroll
      for (int c = 0; c < 4; ++c)
        acc[q][c] = __builtin_amdgcn_mfma_f32_16x16x32_bf16(av[q], bv[c], acc[q][c], 0, 0, 0);
    __builtin_amdgcn_s_barrier();   // all waves done reading buf before reuse
  }

  // Final tile
  __builtin_amdgcn_s_waitcnt(WAIT_VM0);
  __builtin_amdgcn_s_barrier();
  {
    const int boff = ((niter - 1) & 1) << 13;
    bf16x8 av[4], bv[4];
#pragma unroll
    for (int q = 0; q < 4; ++q) av[q] = *reinterpret_cast<const bf16x8*>(lds + boff + offA[q]);
#pragma unroll
    for (int c = 0; c < 4; ++c) bv[c] = *reinterpret_cast<const bf16x8*>(lds + boff + offB[c]);
#pragma unroll
    for (int q = 0; q < 4; ++q)
#pragma unroll
      for (int c = 0; c < 4; ++c)
        acc[q][c] = __builtin_amdgcn_mfma_f32_16x16x32_bf16(av[q], bv[c], acc[q][c], 0, 0, 0);
  }

  const float* bi = (i == 0) ? b0 : (i == 1) ? b1 : (i == 2) ? b2 :
                    (i == 3) ? b3 : (i == 4) ? b4 : (i == 5) ? b5 : b6;
  // Epilogue: C/D layout row = quad*4 + reg, col = lane&15
#pragma unroll
  for (int c = 0; c < 4; ++c) {
    const int nloc = n0loc + waveN + c * 16 + l15;
    const float bias = bi[nloc];
    const int ncol = i * 1024 + nloc;
#pragma unroll
    for (int q = 0; q < 4; ++q) {
      const int mbase = m0 + waveM + q * 16 + quad * 4;
#pragma unroll
      for (int reg = 0; reg < 4; ++reg)
        out[(size_t)(mbase + reg) * 7168 + ncol] = acc[q][c][reg] + bias;
    }
  }
}

// ---------------------------------------------------------------------------
extern "C" void kernel_launch(void* const* d_in, const int* in_sizes, int n_in,
                              void* d_out, int out_size, void* d_ws, size_t ws_size,
                              hipStream_t stream) {
  const float* input = (const float*)d_in[0];
  const int* perms[7];
  const float* W[7];
  const float* bias[7];
  for (int i = 0; i < 7; ++i) {
    perms[i] = (const int*)d_in[1 + 3 * i];
    W[i]     = (const float*)d_in[2 + 3 * i];
    bias[i]  = (const float*)d_in[3 + 3 * i];
  }
  char* ws = (char*)d_ws;
  u16* Xb   = (u16*)ws;                               // 2048*17920 bf16 = 73.4 MB
  u16* Wcat = (u16*)(ws + (size_t)2048 * 17920 * 2);  // 18.35M bf16 = 36.7 MB

  k_xbar<<<2048, 256, 0, stream>>>(input, perms[0], perms[1], perms[2], perms[3],
                                   perms[4], perms[5], perms[6], Xb);
  k_wcast<<<17920, 256, 0, stream>>>(W[0], W[1], W[2], W[3], W[4], W[5], W[6], Wcat);
  k_gemm_ms<<<896, 256, 0, stream>>>(Xb, Wcat,
                                     bias[0], bias[1], bias[2], bias[3],
                                     bias[4], bias[5], bias[6],
                                     (float*)d_out);
}

// Round 6
// 290.448 us; speedup vs baseline: 1.0508x; 1.0508x over previous
//
#include <hip/hip_runtime.h>

typedef unsigned short u16;
typedef __bf16 bf16x8 __attribute__((ext_vector_type(8)));
typedef float f32x16 __attribute__((ext_vector_type(16)));

// fp32 -> bf16 round-to-nearest-even (finite, small values; no NaN path)
__device__ __forceinline__ u16 f2bf(float f) {
  unsigned int u = __float_as_uint(f);
  return (u16)((u + 0x7fffu + ((u >> 16) & 1u)) >> 16);
}

// cumK(i) = sum_{i'<i} (8-i')*512 = 256*i*(17-i); K_i = (8-i)*512
__device__ __forceinline__ int cumK(int i) { return 256 * i * (17 - i); }

// ---------------------------------------------------------------------------
// Kernel 1: xbar build. For each batch row b:
//   Xb[b, cumK(i) + j*512 + f] = bf16( sum_g C_i[g,j] * x[b, g*512 + f] )
// ---------------------------------------------------------------------------
__global__ __launch_bounds__(256) void k_xbar(
    const float* __restrict__ x,
    const int* p0, const int* p1, const int* p2, const int* p3,
    const int* p4, const int* p5, const int* p6,
    u16* __restrict__ Xb) {
  __shared__ float sc[448];
  const int b = blockIdx.x;
  const int t = threadIdx.x;
  const int* ps[7] = {p0, p1, p2, p3, p4, p5, p6};
  for (int cell = t; cell < 448; cell += 256) {
    int i = cell >> 6, rem = cell & 63, g = rem >> 3, j = rem & 7;
    int scale = 8 - i;
    float v = 0.f;
    if (j < scale) {
      const int* p = ps[i];
      int cnt = 0;
      for (int s = 0; s < 12; ++s) cnt += (p[s * scale + j] == g) ? 1 : 0;
      v = (float)cnt * (1.0f / 12.0f);
    }
    sc[cell] = v;
  }
  __syncthreads();
  const int u = t & 63;
  const int wv = t >> 6;
  const float4* xrow = reinterpret_cast<const float4*>(x + (size_t)b * 4096);
  float4 xr0[8], xr1[8];
#pragma unroll
  for (int g = 0; g < 8; ++g) {
    xr0[g] = xrow[g * 128 + u * 2];
    xr1[g] = xrow[g * 128 + u * 2 + 1];
  }
  u16* orow = Xb + (size_t)b * 17920;
  for (int s = wv; s < 35; s += 4) {
    int i = 0, rem = s;                 // wave-uniform decode of (i, j)
    while (rem >= 8 - i) { rem -= 8 - i; ++i; }
    const int j = rem;
    float4 A0 = make_float4(0.f, 0.f, 0.f, 0.f);
    float4 A1 = make_float4(0.f, 0.f, 0.f, 0.f);
#pragma unroll
    for (int g = 0; g < 8; ++g) {
      const float c = sc[i * 64 + g * 8 + j];
      A0.x += c * xr0[g].x; A0.y += c * xr0[g].y;
      A0.z += c * xr0[g].z; A0.w += c * xr0[g].w;
      A1.x += c * xr1[g].x; A1.y += c * xr1[g].y;
      A1.z += c * xr1[g].z; A1.w += c * xr1[g].w;
    }
    uint4 o;
    o.x = (unsigned)f2bf(A0.x) | ((unsigned)f2bf(A0.y) << 16);
    o.y = (unsigned)f2bf(A0.z) | ((unsigned)f2bf(A0.w) << 16);
    o.z = (unsigned)f2bf(A1.x) | ((unsigned)f2bf(A1.y) << 16);
    o.w = (unsigned)f2bf(A1.z) | ((unsigned)f2bf(A1.w) << 16);
    *reinterpret_cast<uint4*>(orow + cumK(i) + j * 512 + u * 8) = o;
  }
}

// ---------------------------------------------------------------------------
// Kernel 2: cast-copy W_i fp32 -> concatenated bf16 Wcat (linear copy).
// ---------------------------------------------------------------------------
__global__ __launch_bounds__(256) void k_wcast(
    const float* W0, const float* W1, const float* W2, const float* W3,
    const float* W4, const float* W5, const float* W6,
    u16* __restrict__ Wcat) {
  int i = 0, rem = blockIdx.x;
  while (rem >= (8 - i) * 512) { rem -= (8 - i) * 512; ++i; }
  const float* Wi = (i == 0) ? W0 : (i == 1) ? W1 : (i == 2) ? W2 :
                    (i == 3) ? W3 : (i == 4) ? W4 : (i == 5) ? W5 : W6;
  const int t = threadIdx.x;
  const float4 w = reinterpret_cast<const float4*>(Wi)[(size_t)rem * 256 + t];
  ushort4 o;
  o.x = f2bf(w.x); o.y = f2bf(w.y); o.z = f2bf(w.z); o.w = f2bf(w.w);
  reinterpret_cast<ushort4*>(Wcat + ((size_t)cumK(i) + rem) * 1024)[t] = o;
}

// ---------------------------------------------------------------------------
// Kernel 3: multi-scale bf16 MFMA GEMM, 2-stage dbuf, BK=64 (R4 winner
// structure: 64 KB LDS, 2 blocks/CU — R5 proved BK=32/5-blocks regresses),
// now with 32x32x16 MFMA fragments (2382 vs 2075 TF ubench; 16 MFMA/iter
// instead of 32 -> ~15% less matrix-pipe time, same LDS traffic).
// Per iter: issue next tile's 8 global_load_lds, s_waitcnt vmcnt(8) (wait
// ONLY the previous tile — current loads stay in flight across the barrier),
// s_barrier, 16x ds_read_b128 + 16 MFMA, s_barrier.
// LDS rows 128 B (one bank period); chunk c of row r at slot (c+r)&7.
// XCD swizzle: blockIdx%8 = XCD owns a 4m x 2n region per scale.
// Scale order {0,1,4,2,5,3,6} balances per-CU work across dispatch phases.
// ---------------------------------------------------------------------------
__device__ __forceinline__ void gl_lds16(const u16* g, u16* l) {
  __builtin_amdgcn_global_load_lds(
      (const __attribute__((address_space(1))) void*)g,
      (__attribute__((address_space(3))) void*)l, 16, 0, 0);
}

#define WAIT_VM8 0x0F78   // vmcnt=8, expcnt=7(nowait), lgkmcnt=15(nowait)
#define WAIT_VM0 0x0F70   // vmcnt=0, expcnt=7, lgkmcnt=15

__global__ __launch_bounds__(256) void k_gemm_ms(
    const u16* __restrict__ Xb, const u16* __restrict__ Wcat,
    const float* b0, const float* b1, const float* b2, const float* b3,
    const float* b4, const float* b5, const float* b6,
    float* __restrict__ out) {
  __shared__ u16 lds[2 * 16384];      // buf b: A at b*16384, B at b*16384+8192
  const int r = blockIdx.x >> 7;
  const int i = (r == 0) ? 0 : (r == 1) ? 1 : (r == 2) ? 4 :
                (r == 3) ? 2 : (r == 4) ? 5 : (r == 5) ? 3 : 6;
  const int s = blockIdx.x & 127;
  const int region = s & 7;           // -> XCD (blockIdx % 8)
  const int k = s >> 3;               // 0..15 within region
  const int mq = region >> 1;         // 0..3
  const int nq = region & 1;          // 0..1
  const int m0 = (mq * 4 + (k & 3)) * 128;
  const int n0loc = (nq * 4 + (k >> 2)) * 128;
  const int K = (8 - i) * 512;
  const int niter = K >> 6;           // 64,56,48,40,32,24,16
  const size_t baseB = (size_t)cumK(i) * 1024;

  const int tid = threadIdx.x;
  const int lane = tid & 63;
  const int wave = tid >> 6;
  const int l31 = lane & 31;
  const int half = lane >> 5;         // k-half within K=16 step
  const int waveM = (wave >> 1) * 64;
  const int waveN = (wave & 1) * 64;

  // Staging: per matrix, tile = 128 rows x 128 B = 1024 chunks of 16 B;
  // 4 chunks/thread. Swizzle: chunk for slot sslot of row srow = (sslot-srow)&7.
  const int srow = tid >> 3;          // 0..31
  const int sslot = tid & 7;
  const int gch = (sslot - srow) & 7;
  const u16* pA0 = Xb + (size_t)(m0 + srow) * 17920 + cumK(i) + gch * 8;
  const u16* pB0 = Wcat + baseB + (size_t)(n0loc + srow) * K + gch * 8;
  const size_t strideAj = (size_t)32 * 17920;
  const size_t strideBj = (size_t)32 * K;
  u16* lA0 = lds + tid * 8;
  u16* lB0 = lds + 8192 + tid * 8;

  // LDS read offsets (u16, buffer 0): row*64 + slot*8, slot=((kk*2+half)+row)&7.
  // A frag fm: row = waveM + fm*32 + l31; B frag fn: row = waveN + fn*32 + l31.
  int offA[4][2], offB[4][2];
#pragma unroll
  for (int kk = 0; kk < 4; ++kk) {
#pragma unroll
    for (int f = 0; f < 2; ++f) {
      int rowA = waveM + f * 32 + l31;
      offA[kk][f] = rowA * 64 + (((kk * 2 + half) + rowA) & 7) * 8;
      int rowB = waveN + f * 32 + l31;
      offB[kk][f] = 8192 + rowB * 64 + (((kk * 2 + half) + rowB) & 7) * 8;
    }
  }

  f32x16 acc[2][2];
#pragma unroll
  for (int q = 0; q < 2; ++q)
#pragma unroll
    for (int c = 0; c < 2; ++c)
      acc[q][c] = (f32x16)(0.f);

  // Prologue: tile 0 -> buffer 0
#pragma unroll
  for (int j = 0; j < 4; ++j) {
    gl_lds16(pA0 + j * strideAj, lA0 + j * 2048);
    gl_lds16(pB0 + j * strideBj, lB0 + j * 2048);
  }

  for (int kt = 0; kt < niter - 1; ++kt) {
    // Issue next tile into the other buffer (stays in flight past barrier)
    const size_t ko = (size_t)(kt + 1) * 64;
    const int nb = ((kt + 1) & 1) << 14;
#pragma unroll
    for (int j = 0; j < 4; ++j) {
      gl_lds16(pA0 + j * strideAj + ko, lA0 + nb + j * 2048);
      gl_lds16(pB0 + j * strideBj + ko, lB0 + nb + j * 2048);
    }
    __builtin_amdgcn_s_waitcnt(WAIT_VM8);   // previous tile's 8 loads done
    __builtin_amdgcn_s_barrier();
    const int boff = (kt & 1) << 14;
#pragma unroll
    for (int kk = 0; kk < 4; ++kk) {
      bf16x8 av[2], bv[2];
#pragma unroll
      for (int f = 0; f < 2; ++f) {
        av[f] = *reinterpret_cast<const bf16x8*>(lds + boff + offA[kk][f]);
        bv[f] = *reinterpret_cast<const bf16x8*>(lds + boff + offB[kk][f]);
      }
#pragma unroll
      for (int q = 0; q < 2; ++q)
#pragma unroll
        for (int c = 0; c < 2; ++c)
          acc[q][c] = __builtin_amdgcn_mfma_f32_32x32x16_bf16(av[q], bv[c], acc[q][c], 0, 0, 0);
    }
    __builtin_amdgcn_s_barrier();   // all waves done reading buf before reuse
  }

  // Final tile
  __builtin_amdgcn_s_waitcnt(WAIT_VM0);
  __builtin_amdgcn_s_barrier();
  {
    const int boff = ((niter - 1) & 1) << 14;
#pragma unroll
    for (int kk = 0; kk < 4; ++kk) {
      bf16x8 av[2], bv[2];
#pragma unroll
      for (int f = 0; f < 2; ++f) {
        av[f] = *reinterpret_cast<const bf16x8*>(lds + boff + offA[kk][f]);
        bv[f] = *reinterpret_cast<const bf16x8*>(lds + boff + offB[kk][f]);
      }
#pragma unroll
      for (int q = 0; q < 2; ++q)
#pragma unroll
        for (int c = 0; c < 2; ++c)
          acc[q][c] = __builtin_amdgcn_mfma_f32_32x32x16_bf16(av[q], bv[c], acc[q][c], 0, 0, 0);
    }
  }

  const float* bi = (i == 0) ? b0 : (i == 1) ? b1 : (i == 2) ? b2 :
                    (i == 3) ? b3 : (i == 4) ? b4 : (i == 5) ? b5 : b6;
  // Epilogue: 32x32 C/D layout: col = lane&31,
  // row = (reg&3) + 8*(reg>>2) + 4*(lane>>5)   [HW-verified m74/m101]
#pragma unroll
  for (int c = 0; c < 2; ++c) {
    const int nloc = n0loc + waveN + c * 32 + l31;
    const float bias = bi[nloc];
    const int ncol = i * 1024 + nloc;
#pragma unroll
    for (int q = 0; q < 2; ++q) {
      const int mbase = m0 + waveM + q * 32 + 4 * half;
#pragma unroll
      for (int reg = 0; reg < 16; ++reg) {
        const int row = mbase + (reg & 3) + 8 * (reg >> 2);
        out[(size_t)row * 7168 + ncol] = acc[q][c][reg] + bias;
      }
    }
  }
}

// ---------------------------------------------------------------------------
extern "C" void kernel_launch(void* const* d_in, const int* in_sizes, int n_in,
                              void* d_out, int out_size, void* d_ws, size_t ws_size,
                              hipStream_t stream) {
  const float* input = (const float*)d_in[0];
  const int* perms[7];
  const float* W[7];
  const float* bias[7];
  for (int i = 0; i < 7; ++i) {
    perms[i] = (const int*)d_in[1 + 3 * i];
    W[i]     = (const float*)d_in[2 + 3 * i];
    bias[i]  = (const float*)d_in[3 + 3 * i];
  }
  char* ws = (char*)d_ws;
  u16* Xb   = (u16*)ws;                               // 2048*17920 bf16 = 73.4 MB
  u16* Wcat = (u16*)(ws + (size_t)2048 * 17920 * 2);  // 18.35M bf16 = 36.7 MB

  k_xbar<<<2048, 256, 0, stream>>>(input, perms[0], perms[1], perms[2], perms[3],
                                   perms[4], perms[5], perms[6], Xb);
  k_wcast<<<17920, 256, 0, stream>>>(W[0], W[1], W[2], W[3], W[4], W[5], W[6], Wcat);
  k_gemm_ms<<<896, 256, 0, stream>>>(Xb, Wcat,
                                     bias[0], bias[1], bias[2], bias[3],
                                     bias[4], bias[5], bias[6],
                                     (float*)d_out);
}